// Round 7
// baseline (196.710 us; speedup 1.0000x reference)
//
#include <hip/hip_runtime.h>
#include <hip/hip_fp16.h>
#include <math.h>

#define NPTS   131072
#define NB     32
#define HD     64
#define NSEG   65
#define PSTR   65            // padded Ps/Qs row stride (65 = 1 mod 32 -> bank-spread)
#define CAPN   483           // 22-ary 2-level: 484 intervals max
#define NODEH  24            // halfs per node: 21 keys + 3 pad(+inf)
#define TREEH  (23 * NODEH)  // 552 halfs per flow block
#define LIMIT  10.0f
#define RANGE  10.001f
#define CLAMPV 10000.0f
#define MAGIC  0xC0FFEE01u

// d_ws layout (bytes)
#define AB_BYTES   (NB * 512 * 16)          // float4[NB][512], intervals 0..483 used
#define TREE_OFF   AB_BYTES                 // u16[NB][TREEH]
#define TREE_BYTES (NB * TREEH * 2)
#define FLAG_OFF   (TREE_OFF + TREE_BYTES)  // uint[NB]

__device__ __forceinline__ int count21(const unsigned short* node, __half2 z) {
    const uint4* q = (const uint4*)node;
    uint4 A = q[0], B = q[1], C = q[2];            // 3 independent ds_read_b128
    unsigned int w[12] = {A.x, A.y, A.z, A.w, B.x, B.y, B.z, B.w, C.x, C.y, C.z, C.w};
    __half2 s = __hlt2(*(const __half2*)&w[0], z);
    #pragma unroll
    for (int i = 1; i < 12; ++i) s = __hadd2(s, __hlt2(*(const __half2*)&w[i], z));
    return (int)(__low2float(s) + __high2float(s));
}

__global__ __launch_bounds__(256) void realnvp_fused(
    const float* __restrict__ x,
    const float* __restrict__ W1, const float* __restrict__ b1,
    const float* __restrict__ W2, const float* __restrict__ b2,
    const float* __restrict__ W3, const float* __restrict__ b3,
    const float* __restrict__ loc, const float* __restrict__ log_scale,
    float* __restrict__ out, char* __restrict__ wsb)
{
    __shared__ __align__(16) float smf[14032];     // 56.1 KB union: build scratch / trees
    const int tid = threadIdx.x;
    const int bid = blockIdx.x;
    unsigned int* fl = (unsigned int*)(wsb + FLAG_OFF);

    // ---------------- phase 1: WGs 0..31 build their flow block ----------------
    if (bid < NB) {
        float* W2s = smf;                // 4096
        float* Ps  = smf + 4096;         // 4225 (padded 65x65)
        float* Qs  = smf + 8321;         // 4225
        float* w1s = smf + 12546;
        float* b1s = smf + 12610;
        float* b2s = smf + 12674;
        float* w3a = smf + 12738;
        float* w3b = smf + 12802;
        float* trC = smf + 12866;        // 64
        float* tsC = smf + 12930;        // 64
        float* bufB= smf + 12994;        // 484
        float* Ts  = smf + 13478;        // 484
        int*   ksC = (int*)(smf + 13962);
        int*   cntp= (int*)(smf + 14026);
        const int p = bid;

        if (p == 0 && tid == 0)
            __hip_atomic_store(out, 0.0f, __ATOMIC_RELAXED, __HIP_MEMORY_SCOPE_AGENT);

        for (int i = tid; i < HD * HD; i += 256) W2s[i] = W2[p * HD * HD + i];
        if (tid < HD) {
            w1s[tid] = W1[p * HD + tid];
            b1s[tid] = b1[p * HD + tid];
            b2s[tid] = b2[p * HD + tid];
            w3a[tid] = W3[p * 2 * HD + 2 * tid + 0];
            w3b[tid] = W3[p * 2 * HD + 2 * tid + 1];
        }
        if (tid == 0) *cntp = 0;
        __syncthreads();

        if (tid < HD) {                  // coarse kinks
            float w = w1s[tid], b = b1s[tid];
            float t = (w != 0.0f) ? (-b / w) : INFINITY;
            if (!(t == t)) t = INFINITY;
            trC[tid] = t;
        }
        __syncthreads();
        if (tid < HD) {                  // stable rank sort of 64
            float v = trC[tid];
            int r = 0;
            for (int j = 0; j < HD; ++j) {
                float u = trC[j];
                r += (u < v) || (u == v && j < tid);
            }
            tsC[r] = v; ksC[r] = tid;
        }
        __syncthreads();

        // prefix-sweep P/Q per channel j (padded stride)
        if (tid < HD) {
            const int j = tid;
            float Pv = 0.0f, Qv = b2s[j];
            for (int k = 0; k < HD; ++k) {
                float w = w1s[k], b = b1s[k];
                bool act = (w < 0.0f) || (w == 0.0f && b > 0.0f);
                if (act) {
                    float wij = W2s[k * HD + j];
                    Pv = fmaf(wij, w, Pv);
                    Qv = fmaf(wij, b, Qv);
                }
            }
            Ps[j] = Pv; Qs[j] = Qv;
            for (int s = 1; s <= HD; ++s) {
                const int k = ksC[s - 1];
                const float w = w1s[k];
                if (w != 0.0f && tsC[s - 1] < 3.0e38f && tsC[s - 1] > -3.0e38f) {
                    float sgn = (w > 0.0f) ? 1.0f : -1.0f;
                    float wij = W2s[k * HD + j];
                    Pv = fmaf(sgn * wij, w,      Pv);
                    Qv = fmaf(sgn * wij, b1s[k], Qv);
                }
                Ps[s * PSTR + j] = Pv; Qs[s * PSTR + j] = Qv;
            }
        }
        __syncthreads();

        // collect refined breakpoints within (-RANGE, RANGE)
        if (tid < HD) {
            float t = tsC[tid];
            if (t > -RANGE && t < RANGE) {
                int i = atomicAdd(cntp, 1);
                if (i < CAPN) bufB[i] = t;
            }
        }
        for (int task = tid; task < NSEG * HD; task += 256) {
            const int s = task >> 6, j = task & (HD - 1);
            float Pv = Ps[s * PSTR + j], Qv = Qs[s * PSTR + j];
            if (Pv != 0.0f) {
                float zc = -Qv / Pv;
                float lo = (s == 0)  ? -RANGE : fmaxf(tsC[s - 1], -RANGE);
                float hi = (s == HD) ?  RANGE : fminf(tsC[s],  RANGE);
                if (zc > lo && zc < hi) {
                    int i = atomicAdd(cntp, 1);
                    if (i < CAPN) bufB[i] = zc;
                }
            }
        }
        __syncthreads();
        const int n = min(*cntp, CAPN);

        for (int i = tid; i < n; i += 256) {   // stable rank sort n refined
            float v = bufB[i];
            int r = 0;
            for (int j = 0; j < n; ++j) {
                float u = bufB[j];
                r += (u < v) || (u == v && j < i);
            }
            Ts[r] = v;
        }
        __syncthreads();

        // 22-ary 2-level fp16 tree: L0 keys T[22i+21]; L1 node c keys T[22c+j]
        unsigned short* treeG = (unsigned short*)(wsb + TREE_OFF);
        for (int e = tid; e < TREEH; e += 256) {
            const int node = e / NODEH, slot = e % NODEH;
            int r = -1;
            if (slot < 21) r = (node == 0) ? (22 * slot + 21) : (22 * (node - 1) + slot);
            unsigned short hv = 0x7C00;        // +inf
            if (r >= 0 && r < n) {
                __half h = __float2half_rn(Ts[r]);
                hv = *(const unsigned short*)&h;
            }
            treeG[p * TREEH + e] = hv;
        }

        // ABCD per interval u in [0, n]
        const float b30 = b3[p * 2 + 0], b31 = b3[p * 2 + 1];
        float4* AB = (float4*)wsb;
        for (int u = tid; u <= n; u += 256) {
            float lo = (u == 0) ? -RANGE : Ts[u - 1];
            float hi = (u == n) ?  RANGE : Ts[u];
            float zm = 0.5f * (lo + hi);
            int s = 0;
            for (int k = 0; k < HD; ++k) s += (tsC[k] < zm);
            float Ash = 0.f, Bsh = 0.f, Asc = 0.f, Bsc = 0.f;
            for (int j = 0; j < HD; ++j) {
                float Pv = Ps[s * PSTR + j], Qv = Qs[s * PSTR + j];
                if (fmaf(Pv, zm, Qv) > 0.0f) {
                    Ash = fmaf(w3a[j], Pv, Ash); Bsh = fmaf(w3a[j], Qv, Bsh);
                    Asc = fmaf(w3b[j], Pv, Asc); Bsc = fmaf(w3b[j], Qv, Bsc);
                }
            }
            AB[(p << 9) + u] = make_float4(Ash, Bsh + b30, Asc, Bsc + b31);
        }

        __syncthreads();
        __threadfence();                       // publish tree/AB/out at agent scope
        if (tid == 0)
            __hip_atomic_store(&fl[p], MAGIC, __ATOMIC_RELEASE, __HIP_MEMORY_SCOPE_AGENT);
    }

    // ---------------- handshake: wait for all 32 builders ----------------
    if (tid < NB) {
        while (__hip_atomic_load(&fl[tid], __ATOMIC_ACQUIRE, __HIP_MEMORY_SCOPE_AGENT) != MAGIC)
            __builtin_amdgcn_s_sleep(2);
    }
    __syncthreads();

    // ---------------- phase 2: all 512 WGs evaluate ----------------
    unsigned short* tree = (unsigned short*)smf;           // 35.3 KB, overwrites scratch
    {
        const uint4* tg = (const uint4*)(wsb + TREE_OFF);
        uint4* tl = (uint4*)tree;
        for (int i = tid; i < NB * TREEH / 8; i += 256) tl[i] = tg[i];
    }
    __syncthreads();

    const float4* AB = (const float4*)wsb;
    const int g = bid * 256 + tid;
    float2 xv = ((const float2*)x)[g];
    float za = xv.x, zb = xv.y;
    float ld = 0.0f;
    bool mask = true;

    for (int t = 0; t < NB; ++t) {
        const int p = NB - 1 - t;

        bool in1 = (fabsf(za) < LIMIT) && (fabsf(zb) < LIMIT);
        mask = mask && in1;
        if (mask) {
            float na = fminf(fmaxf(zb, -CLAMPV), CLAMPV);
            float nb = fminf(fmaxf(za, -CLAMPV), CLAMPV);
            za = na; zb = nb;
        }
        const float z1 = za, z2 = zb;

        const __half2 zh = __float2half2_rn(z1);
        const unsigned short* tb = tree + p * TREEH;
        int c0 = count21(tb, zh);
        int c1 = count21(tb + NODEH + NODEH * c0, zh);
        int u = 22 * c0 + c1;

        float4 abcd = AB[(p << 9) + u];
        const float shift = fmaf(abcd.x, z1, abcd.y);
        const float scale = fmaf(abcd.z, z1, abcd.w);
        float z2n = (z2 - shift) * __expf(-scale);

        bool in2 = (fabsf(za) < LIMIT) && (fabsf(zb) < LIMIT);
        mask = mask && in2;
        if (mask) {
            za = fminf(fmaxf(z1,  -CLAMPV), CLAMPV);
            zb = fminf(fmaxf(z2n, -CLAMPV), CLAMPV);
            ld -= scale;
        }
    }

    const float l0 = loc[0], l1 = loc[1];
    const float ls0 = log_scale[0], ls1 = log_scale[1];
    const float e0 = __expf(-ls0), e1 = __expf(-ls1);
    const float t0 = (za - l0) * e0, t1 = (zb - l1) * e1;
    float val = -1.8378770664093453f - (ls0 + ls1)
                - 0.5f * (t0 * t0 + t1 * t1) + ld;

    #pragma unroll
    for (int off = 32; off > 0; off >>= 1)
        val += __shfl_down(val, off, 64);
    if ((tid & 63) == 0) atomicAdd(out, val);
}

extern "C" void kernel_launch(void* const* d_in, const int* in_sizes, int n_in,
                              void* d_out, int out_size, void* d_ws, size_t ws_size,
                              hipStream_t stream) {
    const float* x   = (const float*)d_in[0];
    const float* W1  = (const float*)d_in[1];
    const float* b1  = (const float*)d_in[2];
    const float* W2  = (const float*)d_in[3];
    const float* b2  = (const float*)d_in[4];
    const float* W3  = (const float*)d_in[5];
    const float* b3  = (const float*)d_in[6];
    const float* loc = (const float*)d_in[7];
    const float* lsc = (const float*)d_in[8];

    realnvp_fused<<<NPTS / 256, 256, 0, stream>>>(
        x, W1, b1, W2, b2, W3, b3, loc, lsc, (float*)d_out, (char*)d_ws);
}

// Round 8
// 140.331 us; speedup vs baseline: 1.4018x; 1.4018x over previous
//
#include <hip/hip_runtime.h>
#include <math.h>

#define NPTS   131072
#define NB     32
#define HD     64
#define NSEG   65
#define PSTR   65            // padded Ps/Qs row stride (65 mod 32 = 1 -> bank-spread)
#define CAPN   483           // max refined breakpoints kept
#define CELLS  2048          // uniform grid over (-10,10)
#define LIMIT  10.0f
#define RANGE  10.001f
#define CLAMPV 10000.0f

// ws: cellTab float4[NB][CELLS] = 1 MB exactly
// -------- build: collapse MLP to piecewise-linear, rasterize onto the grid --------
__global__ __launch_bounds__(512) void build_cells(
    const float* __restrict__ W1, const float* __restrict__ b1,
    const float* __restrict__ W2, const float* __restrict__ b2,
    const float* __restrict__ W3, const float* __restrict__ b3,
    float* __restrict__ ws, float* __restrict__ out)
{
    const int p = blockIdx.x;
    const int tid = threadIdx.x;
    if (p == 0 && tid == 0) out[0] = 0.0f;

    __shared__ __align__(16) float W2s[HD * HD];     // later reused: pieceAB float4[CAPN+1]
    __shared__ float Ps[NSEG * PSTR], Qs[NSEG * PSTR];
    __shared__ float w1s[HD], b1s[HD], b2s[HD], w3a[HD], w3b[HD];
    __shared__ float trC[HD], tsC[HD];
    __shared__ int   ksC[HD];
    __shared__ float bufB[CAPN], Ts[CAPN];
    __shared__ int cnt;

    for (int i = tid; i < HD * HD; i += 512) W2s[i] = W2[p * HD * HD + i];
    if (tid < HD) {
        w1s[tid] = W1[p * HD + tid];
        b1s[tid] = b1[p * HD + tid];
        b2s[tid] = b2[p * HD + tid];
        w3a[tid] = W3[p * 2 * HD + 2 * tid + 0];
        w3b[tid] = W3[p * 2 * HD + 2 * tid + 1];
    }
    if (tid == 0) cnt = 0;
    __syncthreads();

    if (tid < HD) {                 // coarse kinks t = -b/w (w==0 -> +inf)
        float w = w1s[tid], b = b1s[tid];
        float t = (w != 0.0f) ? (-b / w) : INFINITY;
        if (!(t == t)) t = INFINITY;
        trC[tid] = t;
    }
    __syncthreads();
    if (tid < HD) {                 // stable rank sort 64
        float v = trC[tid];
        int r = 0;
        for (int j = 0; j < HD; ++j) {
            float u = trC[j];
            r += (u < v) || (u == v && j < tid);
        }
        tsC[r] = v; ksC[r] = tid;
    }
    __syncthreads();

    // prefix-sweep P/Q per channel j across the 65 coarse segments
    if (tid < HD) {
        const int j = tid;
        float Pv = 0.0f, Qv = b2s[j];
        for (int k = 0; k < HD; ++k) {          // active set at z = -inf
            float w = w1s[k], b = b1s[k];
            if ((w < 0.0f) || (w == 0.0f && b > 0.0f)) {
                float wij = W2s[k * HD + j];
                Pv = fmaf(wij, w, Pv);
                Qv = fmaf(wij, b, Qv);
            }
        }
        Ps[j] = Pv; Qs[j] = Qv;
        for (int s = 1; s <= HD; ++s) {         // cross sorted kink s-1
            const int k = ksC[s - 1];
            const float w = w1s[k];
            if (w != 0.0f && tsC[s - 1] < 3.0e38f && tsC[s - 1] > -3.0e38f) {
                float sgn = (w > 0.0f) ? 1.0f : -1.0f;
                float wij = W2s[k * HD + j];
                Pv = fmaf(sgn * wij, w,      Pv);
                Qv = fmaf(sgn * wij, b1s[k], Qv);
            }
            Ps[s * PSTR + j] = Pv; Qs[s * PSTR + j] = Qv;
        }
    }
    __syncthreads();

    // refined breakpoints in (-RANGE, RANGE): coarse kinks + layer-2 zero crossings
    if (tid < HD) {
        float t = tsC[tid];
        if (t > -RANGE && t < RANGE) {
            int i = atomicAdd(&cnt, 1);
            if (i < CAPN) bufB[i] = t;
        }
    }
    for (int task = tid; task < NSEG * HD; task += 512) {
        const int s = task >> 6, j = task & (HD - 1);
        float Pv = Ps[s * PSTR + j], Qv = Qs[s * PSTR + j];
        if (Pv != 0.0f) {
            float zc = -Qv / Pv;
            float lo = (s == 0)  ? -RANGE : fmaxf(tsC[s - 1], -RANGE);
            float hi = (s == HD) ?  RANGE : fminf(tsC[s],  RANGE);
            if (zc > lo && zc < hi) {
                int i = atomicAdd(&cnt, 1);
                if (i < CAPN) bufB[i] = zc;
            }
        }
    }
    __syncthreads();
    const int n = min(cnt, CAPN);

    for (int i = tid; i < n; i += 512) {        // stable rank sort n refined
        float v = bufB[i];
        int r = 0;
        for (int j = 0; j < n; ++j) {
            float u = bufB[j];
            r += (u < v) || (u == v && j < i);
        }
        Ts[r] = v;
    }
    __syncthreads();

    // piece ABCD for intervals u in [0, n] -> LDS (reuse W2s space)
    float4* pieceAB = (float4*)W2s;
    const float b30 = b3[p * 2 + 0], b31 = b3[p * 2 + 1];
    for (int u = tid; u <= n; u += 512) {
        float lo = (u == 0) ? -RANGE : Ts[u - 1];
        float hi = (u == n) ?  RANGE : Ts[u];
        float zm = 0.5f * (lo + hi);
        int s = 0;
        for (int k = 0; k < HD; ++k) s += (tsC[k] < zm);
        float Ash = 0.f, Bsh = 0.f, Asc = 0.f, Bsc = 0.f;
        for (int j = 0; j < HD; ++j) {
            float Pv = Ps[s * PSTR + j], Qv = Qs[s * PSTR + j];
            if (fmaf(Pv, zm, Qv) > 0.0f) {
                Ash = fmaf(w3a[j], Pv, Ash); Bsh = fmaf(w3a[j], Qv, Bsh);
                Asc = fmaf(w3b[j], Pv, Asc); Bsc = fmaf(w3b[j], Qv, Bsc);
            }
        }
        pieceAB[u] = make_float4(Ash, Bsh + b30, Asc, Bsc + b31);
    }
    __syncthreads();

    // rasterize: each thread fills a contiguous run of cells (merge walk)
    float4* cellTab = (float4*)ws + (size_t)p * CELLS;
    const float cw = 20.0f / CELLS;
    const int cpt = CELLS / 512;                // 4 cells per thread
    {
        const int c0 = tid * cpt;
        float zm0 = -10.0f + (c0 + 0.5f) * cw;
        int u = 0;
        for (int j = 0; j < n; ++j) u += (Ts[j] < zm0);   // broadcast reads
        for (int q = 0; q < cpt; ++q) {
            float zm = -10.0f + (c0 + q + 0.5f) * cw;
            while (u < n && Ts[u] < zm) ++u;
            cellTab[c0 + q] = pieceAB[u];       // coalesced 16B stores
        }
    }
}

// -------- eval: zero LDS; per step = 1 divergent L1/L2 gather + 2 FMA + exp --------
__global__ __launch_bounds__(256) void realnvp_eval(
    const float* __restrict__ x,
    const float* __restrict__ ws,
    const float* __restrict__ loc, const float* __restrict__ log_scale,
    float* __restrict__ out)
{
    const int tid = threadIdx.x;
    const int g = blockIdx.x * 256 + tid;
    const float4* cellTab = (const float4*)ws;

    float2 xv = ((const float2*)x)[g];
    float za = xv.x, zb = xv.y;
    float ld = 0.0f;
    bool mask = true;

    const float toCell = (float)CELLS / 20.0f;

    for (int t = 0; t < NB; ++t) {
        const int p = NB - 1 - t;

        bool in1 = (fabsf(za) < LIMIT) && (fabsf(zb) < LIMIT);
        mask = mask && in1;
        if (mask) {
            float na = fminf(fmaxf(zb, -CLAMPV), CLAMPV);
            float nb = fminf(fmaxf(za, -CLAMPV), CLAMPV);
            za = na; zb = nb;
        }
        const float z1 = za, z2 = zb;

        int cell = (int)((z1 + 10.0f) * toCell);
        cell = min(max(cell, 0), CELLS - 1);

        float4 abcd = cellTab[(p << 11) + cell];
        const float shift = fmaf(abcd.x, z1, abcd.y);
        const float scale = fmaf(abcd.z, z1, abcd.w);
        float z2n = (z2 - shift) * __expf(-scale);

        bool in2 = (fabsf(za) < LIMIT) && (fabsf(zb) < LIMIT);
        mask = mask && in2;
        if (mask) {
            za = fminf(fmaxf(z1,  -CLAMPV), CLAMPV);
            zb = fminf(fmaxf(z2n, -CLAMPV), CLAMPV);
            ld -= scale;
        }
    }

    const float l0 = loc[0], l1 = loc[1];
    const float ls0 = log_scale[0], ls1 = log_scale[1];
    const float e0 = __expf(-ls0), e1 = __expf(-ls1);
    const float t0 = (za - l0) * e0, t1 = (zb - l1) * e1;
    float val = -1.8378770664093453f - (ls0 + ls1)
                - 0.5f * (t0 * t0 + t1 * t1) + ld;

    #pragma unroll
    for (int off = 32; off > 0; off >>= 1)
        val += __shfl_down(val, off, 64);
    if ((tid & 63) == 0) atomicAdd(out, val);
}

extern "C" void kernel_launch(void* const* d_in, const int* in_sizes, int n_in,
                              void* d_out, int out_size, void* d_ws, size_t ws_size,
                              hipStream_t stream) {
    const float* x   = (const float*)d_in[0];
    const float* W1  = (const float*)d_in[1];
    const float* b1  = (const float*)d_in[2];
    const float* W2  = (const float*)d_in[3];
    const float* b2  = (const float*)d_in[4];
    const float* W3  = (const float*)d_in[5];
    const float* b3  = (const float*)d_in[6];
    const float* loc = (const float*)d_in[7];
    const float* lsc = (const float*)d_in[8];
    float* out = (float*)d_out;
    float* ws  = (float*)d_ws;

    build_cells<<<NB, 512, 0, stream>>>(W1, b1, W2, b2, W3, b3, ws, out);
    realnvp_eval<<<NPTS / 256, 256, 0, stream>>>(x, ws, loc, lsc, out);
}